// Round 6
// baseline (654.067 us; speedup 1.0000x reference)
//
#include <hip/hip_runtime.h>
#include <hip/hip_bf16.h>

// pooled[s] = sum_k ( S[s,k,:] @ W[k] ) + sum_k count[s,k]*b[k]
// S[s,k,:] = sum of atom rows in segment s with degree k.
//
// Single persistent mega-kernel (512 blocks x 256 thr, co-resident via
// __launch_bounds__(256,2) => 2 blocks/CU x 256 CUs = 512) + 1 tiny memset:
//   phase 1: bucket-fill slots[key*CAP+p]=i  (one pass over atoms)
//   -- grid barrier --
//   phase 2: blocks 0..K-1 first convert W -> bf16 transposed (hidden in
//            gather slack); all waves gather bins. Bin's slot indices staged
//            in per-wave LDS (exec-mask safe, unlike __shfl from inactive
//            lanes, which is undefined and broke R5); 512-B row reads -> S.
//   -- grid barrier --
//   phase 3: MFMA GEMM out = S @ Wb + (cnt . bias), plain stores

#define CAP  64    // max atoms per (segment,degree) bin; Poisson(8.7) -> safe
#define GRID 512
#define TPB  256

typedef short bf16x8 __attribute__((ext_vector_type(8)));
typedef float f32x4  __attribute__((ext_vector_type(4)));

__device__ __forceinline__ unsigned short f2bf(float f) {
    unsigned int u = __builtin_bit_cast(unsigned int, f);
    u += 0x7fffu + ((u >> 16) & 1u);
    return (unsigned short)(u >> 16);
}

__device__ __forceinline__ int deg_of(int i, const int* __restrict__ ds, int K) {
    int k = 0, end = 0;
    for (int kk = 0; kk < K; ++kk) { end += ds[2 * kk + 1]; k += (i >= end) ? 1 : 0; }
    return k;
}

__device__ __forceinline__ float4 f4add(float4 a, float4 b) {
    return make_float4(a.x + b.x, a.y + b.y, a.z + b.z, a.w + b.w);
}

// Device-scope grid barrier; all blocks co-resident by launch-bounds contract.
__device__ __forceinline__ void gbar(unsigned* bar, unsigned target) {
    __threadfence();                       // release my global writes
    __syncthreads();
    if (threadIdx.x == 0) {
        __hip_atomic_fetch_add(bar, 1u, __ATOMIC_ACQ_REL, __HIP_MEMORY_SCOPE_AGENT);
        while (__hip_atomic_load(bar, __ATOMIC_ACQUIRE, __HIP_MEMORY_SCOPE_AGENT) < target)
            __builtin_amdgcn_s_sleep(2);
    }
    __syncthreads();
    __threadfence();                       // acquire remote writes
}

__global__ __launch_bounds__(TPB, 2) void k_mega(
    const float* __restrict__ atoms,
    const float* __restrict__ W,
    const float* __restrict__ bias,
    const int*   __restrict__ ds,
    const int*   __restrict__ mem,
    float*       __restrict__ out,
    unsigned*    __restrict__ cnt,    // [B*K]   (zeroed by memset)
    unsigned*    __restrict__ slots,  // [B*K*CAP]
    unsigned short* __restrict__ Wb,  // [K][128][128] bf16 ([k][col][f])
    unsigned short* __restrict__ S,   // [B*K][128] bf16
    unsigned*    __restrict__ bar,    // barrier counter (zeroed by memset)
    int N, int K, int B)
{
    __shared__ unsigned short wt[128 * 130];
    __shared__ unsigned slbuf[TPB / 64][64];   // per-wave slot-index stage
    const int bid = blockIdx.x, tid = threadIdx.x;
    const int KB = B * K;

    // ---------------- phase 1: bucket fill ----------------
    for (int i = bid * TPB + tid; i < N; i += GRID * TPB) {
        int key = mem[i] * K + deg_of(i, ds, K);
        unsigned p = atomicAdd(&cnt[key], 1u);
        if (p < CAP) slots[(size_t)key * CAP + p] = (unsigned)i;
    }
    gbar(bar, GRID);

    // ---------------- phase 2: wconv (K blocks) + gather ----------------
    if (bid < K) {
        const float* Wk = W + (size_t)bid * 16384;
        unsigned short* Wbk = Wb + (size_t)bid * 16384;
        for (int e = tid; e < 16384; e += TPB) {
            int f = e >> 7, c = e & 127;
            wt[f * 130 + c] = f2bf(Wk[e]);
        }
        __syncthreads();
        for (int e = tid; e < 16384; e += TPB) {
            int c = e >> 7, f = e & 127;
            Wbk[e] = wt[f * 130 + c];
        }
    }

    const int wv   = tid >> 6;                         // wave within block
    const int wid  = bid * (TPB / 64) + wv;            // wave id in grid
    const int nw   = GRID * (TPB / 64);
    const int lane = tid & 63;
    const int rpar = lane >> 5;                        // row parity
    const int f4   = lane & 31;                        // float4 within row
    unsigned* sw = slbuf[wv];

    for (int bin = wid; bin < KB; bin += nw) {
        int n = (int)cnt[bin];
        if (n > CAP) n = CAP;
        // stage the bin's indices: one coalesced 256-B load, wave-private LDS
        sw[lane] = slots[(size_t)bin * CAP + lane];
        float4 A0 = make_float4(0.f, 0.f, 0.f, 0.f);
        float4 A1 = A0, A2 = A0, A3 = A0;
        int j = rpar;
        for (; j + 6 < n; j += 8) {                    // 8 rows in flight/wave
            unsigned r0 = sw[j], r1 = sw[j + 2], r2 = sw[j + 4], r3 = sw[j + 6];
            float4 v0 = *reinterpret_cast<const float4*>(atoms + (size_t)r0 * 128 + f4 * 4);
            float4 v1 = *reinterpret_cast<const float4*>(atoms + (size_t)r1 * 128 + f4 * 4);
            float4 v2 = *reinterpret_cast<const float4*>(atoms + (size_t)r2 * 128 + f4 * 4);
            float4 v3 = *reinterpret_cast<const float4*>(atoms + (size_t)r3 * 128 + f4 * 4);
            A0 = f4add(A0, v0); A1 = f4add(A1, v1);
            A2 = f4add(A2, v2); A3 = f4add(A3, v3);
        }
        for (; j < n; j += 2) {
            unsigned r = sw[j];
            float4 v = *reinterpret_cast<const float4*>(atoms + (size_t)r * 128 + f4 * 4);
            A0 = f4add(A0, v);
        }
        float4 Sm = f4add(f4add(A0, A1), f4add(A2, A3));
        Sm.x += __shfl_xor(Sm.x, 32, 64);              // all lanes active here
        Sm.y += __shfl_xor(Sm.y, 32, 64);
        Sm.z += __shfl_xor(Sm.z, 32, 64);
        Sm.w += __shfl_xor(Sm.w, 32, 64);
        if (rpar == 0) {
            unsigned lo = (unsigned)f2bf(Sm.x) | ((unsigned)f2bf(Sm.y) << 16);
            unsigned hi = (unsigned)f2bf(Sm.z) | ((unsigned)f2bf(Sm.w) << 16);
            *reinterpret_cast<uint2*>(S + (size_t)bin * 128 + f4 * 4) = make_uint2(lo, hi);
        }
    }
    gbar(bar, 2u * GRID);

    // ---------------- phase 3: GEMM out = S @ Wb + cnt.bias ----------------
    const int ntiles = (B / 16) * 4;                   // 16 segs x 32 cols
    const int quad = lane >> 4, cb = lane & 15;
    const int KD = K * 128;
    for (int t = wid; t < ntiles; t += nw) {
        int s0 = (t >> 2) * 16;
        int c0 = (t & 3) * 32;
        f32x4 acc0 = (f32x4){0.f, 0.f, 0.f, 0.f};
        f32x4 acc1 = (f32x4){0.f, 0.f, 0.f, 0.f};
        const unsigned short* Arow = S  + (size_t)(s0 + cb) * KD + quad * 8;
        const unsigned short* B0   = Wb + (size_t)(c0 + cb)      * 128 + quad * 8;
        const unsigned short* B1   = Wb + (size_t)(c0 + 16 + cb) * 128 + quad * 8;
        #pragma unroll 1
        for (int kk = 0; kk < K; ++kk) {
            #pragma unroll
            for (int k0 = 0; k0 < 128; k0 += 32) {
                bf16x8 a  = *reinterpret_cast<const bf16x8*>(Arow + kk * 128 + k0);
                bf16x8 b0 = *reinterpret_cast<const bf16x8*>(B0 + (size_t)kk * 16384 + k0);
                bf16x8 b1 = *reinterpret_cast<const bf16x8*>(B1 + (size_t)kk * 16384 + k0);
                acc0 = __builtin_amdgcn_mfma_f32_16x16x32_bf16(a, b0, acc0, 0, 0, 0);
                acc1 = __builtin_amdgcn_mfma_f32_16x16x32_bf16(a, b1, acc1, 0, 0, 0);
            }
        }
        #pragma unroll
        for (int reg = 0; reg < 4; ++reg) {
            int s = s0 + quad * 4 + reg;
            float b0s = 0.f, b1s = 0.f;
            for (int k = 0; k < K; ++k) {
                float c = (float)cnt[(size_t)s * K + k];
                b0s += c * bias[k * 128 + c0 + cb];
                b1s += c * bias[k * 128 + c0 + 16 + cb];
            }
            out[(size_t)s * 128 + c0 + cb]      = acc0[reg] + b0s;
            out[(size_t)s * 128 + c0 + 16 + cb] = acc1[reg] + b1s;
        }
    }
}

// ---------------- fallback (round-1 fused kernel) if ws too small ----------
#define TM 64
#define LDA 136
#define LDW 136
__global__ __launch_bounds__(256, 2) void degree_affine_pool(
    const float* __restrict__ atoms, const float* __restrict__ W,
    const float* __restrict__ bias, const int* __restrict__ deg_slice,
    const int* __restrict__ membership, float* __restrict__ out, int K)
{
    __shared__ unsigned short Alds[TM * LDA];
    __shared__ unsigned short Wlds[128 * LDW];
    const int bid = blockIdx.x, tid = threadIdx.x;
    int k = -1, tile = 0, acc_t = 0;
    for (int kk = 0; kk < K; ++kk) {
        int c = deg_slice[2 * kk + 1];
        int nt = (c + TM - 1) >> 6;
        if (k < 0 && bid < acc_t + nt) { k = kk; tile = bid - acc_t; }
        acc_t += nt;
    }
    if (k < 0) return;
    const int start = deg_slice[2 * k], cnt = deg_slice[2 * k + 1];
    const int row0 = start + tile * TM;
    const int rows_valid = min(TM, cnt - tile * TM);
    for (int e = tid; e < TM * 32; e += 256) {
        int r = e >> 5, f4 = e & 31;
        float4 v = make_float4(0.f, 0.f, 0.f, 0.f);
        if (r < rows_valid)
            v = *reinterpret_cast<const float4*>(atoms + (size_t)(row0 + r) * 128 + f4 * 4);
        unsigned lo = (unsigned)f2bf(v.x) | ((unsigned)f2bf(v.y) << 16);
        unsigned hi = (unsigned)f2bf(v.z) | ((unsigned)f2bf(v.w) << 16);
        *reinterpret_cast<uint2*>(&Alds[r * LDA + f4 * 4]) = make_uint2(lo, hi);
    }
    const float* Wk = W + (size_t)k * 16384;
    for (int e = tid; e < 8192; e += 256) {
        int c = e & 127, f2 = e >> 7;
        unsigned p = (unsigned)f2bf(Wk[(2 * f2) * 128 + c]) |
                     ((unsigned)f2bf(Wk[(2 * f2 + 1) * 128 + c]) << 16);
        *reinterpret_cast<unsigned*>(&Wlds[c * LDW + 2 * f2]) = p;
    }
    __syncthreads();
    const int wave = tid >> 6, lane = tid & 63, quad = lane >> 4, cb = lane & 15;
    f32x4 acc[8];
    #pragma unroll
    for (int ct = 0; ct < 8; ++ct) acc[ct] = (f32x4){0.f, 0.f, 0.f, 0.f};
    #pragma unroll
    for (int k0 = 0; k0 < 128; k0 += 32) {
        bf16x8 af = *reinterpret_cast<const bf16x8*>(&Alds[(wave * 16 + cb) * LDA + k0 + quad * 8]);
        #pragma unroll
        for (int ct = 0; ct < 8; ++ct) {
            bf16x8 bf = *reinterpret_cast<const bf16x8*>(&Wlds[(ct * 16 + cb) * LDW + k0 + quad * 8]);
            acc[ct] = __builtin_amdgcn_mfma_f32_16x16x32_bf16(af, bf, acc[ct], 0, 0, 0);
        }
    }
    int segs[4]; bool valid[4];
    #pragma unroll
    for (int reg = 0; reg < 4; ++reg) {
        int rl = wave * 16 + quad * 4 + reg;
        valid[reg] = (rl < rows_valid);
        segs[reg] = valid[reg] ? membership[row0 + rl] : 0;
    }
    const float* bk = bias + k * 128;
    #pragma unroll
    for (int ct = 0; ct < 8; ++ct) {
        int col = ct * 16 + cb;
        float bv = bk[col];
        #pragma unroll
        for (int reg = 0; reg < 4; ++reg)
            if (valid[reg])
                __hip_atomic_fetch_add(out + (size_t)segs[reg] * 128 + col,
                                       acc[ct][reg] + bv, __ATOMIC_RELAXED,
                                       __HIP_MEMORY_SCOPE_AGENT);
    }
}
// ---------------------------------------------------------------------------

static inline size_t aln(size_t x) { return (x + 255) & ~(size_t)255; }

extern "C" void kernel_launch(void* const* d_in, const int* in_sizes, int n_in,
                              void* d_out, int out_size, void* d_ws, size_t ws_size,
                              hipStream_t stream) {
    const float* atoms = (const float*)d_in[0];
    const float* W     = (const float*)d_in[1];
    const float* bias  = (const float*)d_in[2];
    const int*   deg   = (const int*)d_in[3];
    const int*   mem   = (const int*)d_in[4];
    float*       out   = (float*)d_out;

    const int K  = in_sizes[3] / 2;      // 11
    const int N  = in_sizes[0] / 128;    // 393216
    const int B  = out_size / 128;       // 4096
    const int KB = B * K;                // 45056 bins

    // workspace plan (~23.6 MB)
    size_t oWb   = 0;                       size_t sWb   = (size_t)K * 16384 * 2;
    size_t oCnt  = aln(oWb + sWb);          size_t sCnt  = (size_t)KB * 4;
    size_t oBar  = aln(oCnt + sCnt);        size_t sBar  = 256;
    size_t oSlot = aln(oBar + sBar);        size_t sSlot = (size_t)KB * CAP * 4;
    size_t oS    = aln(oSlot + sSlot);      size_t sS    = (size_t)KB * 128 * 2;
    size_t total = oS + sS;

    if (ws_size < total || (B & 15) != 0 || K > GRID) {
        (void)hipMemsetAsync(d_out, 0, (size_t)out_size * sizeof(float), stream);
        const int blocks = (N + TM - 1) / TM + K;
        degree_affine_pool<<<blocks, 256, 0, stream>>>(atoms, W, bias, deg, mem, out, K);
        return;
    }

    char* ws = (char*)d_ws;
    unsigned short* Wb    = (unsigned short*)(ws + oWb);
    unsigned*       cnt   = (unsigned*)(ws + oCnt);
    unsigned*       bar   = (unsigned*)(ws + oBar);
    unsigned*       slots = (unsigned*)(ws + oSlot);
    unsigned short* S     = (unsigned short*)(ws + oS);

    // zero cnt + barrier counter (contiguous region)
    (void)hipMemsetAsync(cnt, 0, (oBar + sBar) - oCnt, stream);

    k_mega<<<GRID, TPB, 0, stream>>>(atoms, W, bias, deg, mem, out,
                                     cnt, slots, Wb, S, bar, N, K, B);
}